// Round 4
// baseline (820.814 us; speedup 1.0000x reference)
//
#include <hip/hip_runtime.h>
#include <cstdint>
#include <cstddef>

#define C_DIM 768
#define N_DIM 16384

typedef __attribute__((ext_vector_type(8))) short short8;   // 8 bf16 = 4 VGPRs
typedef __attribute__((ext_vector_type(4))) float f32x4;

__device__ __forceinline__ ushort f2bf(float f) {
    uint32_t u = __float_as_uint(f);
    uint32_t r = 0x7fffu + ((u >> 16) & 1u);   // round-to-nearest-even
    return (ushort)((u + r) >> 16);
}

__device__ __forceinline__ void async_ld16(const void* g, void* l) {
    __builtin_amdgcn_global_load_lds(
        (__attribute__((address_space(1))) void*)g,
        (__attribute__((address_space(3))) void*)l,
        16, 0, 0);
}

template<int N> __device__ __forceinline__ void wait_vmcnt() {
    if constexpr (N == 4)      asm volatile("s_waitcnt vmcnt(4)" ::: "memory");
    else if constexpr (N == 2) asm volatile("s_waitcnt vmcnt(2)" ::: "memory");
    else if constexpr (N == 0) asm volatile("s_waitcnt vmcnt(0)" ::: "memory");
    // N < 0: no wait
}

// ---------------------------------------------------------------------------
// Normalize columns of F (C_DIM x N_DIM) and write transposed bf16:
// T[i][c] = F[c][i] / max(||col_i||, eps).  blockIdx.y selects the input.
// (verified rounds 1-4; unchanged)
// ---------------------------------------------------------------------------
__global__ __launch_bounds__(256) void norm_tr(const float* __restrict__ F0,
                                               ushort* __restrict__ T0,
                                               const float* __restrict__ F1,
                                               ushort* __restrict__ T1) {
    const float*  F = blockIdx.y ? F1 : F0;
    ushort*       T = blockIdx.y ? T1 : T0;
    const int i0 = blockIdx.x * 64;
    const int t  = threadIdx.x;
    const int tx = t & 63;
    const int ty = t >> 6;

    float ss = 0.f;
    for (int c = ty; c < C_DIM; c += 4) {
        float v = F[(size_t)c * N_DIM + i0 + tx];
        ss += v * v;
    }
    __shared__ float red[4][64];
    __shared__ float scale[64];
    red[ty][tx] = ss;
    __syncthreads();
    if (t < 64) {
        float s = red[0][t] + red[1][t] + red[2][t] + red[3][t];
        float n = sqrtf(s);
        scale[t] = 1.0f / fmaxf(n, 1e-12f);
    }
    __syncthreads();

    __shared__ float tile[64][65];
    const int i_l   = t >> 3;
    const int c_off = (t & 7) * 8;
    for (int c0 = 0; c0 < C_DIM; c0 += 64) {
        #pragma unroll
        for (int rr = 0; rr < 16; ++rr) {
            int c_l = rr * 4 + ty;
            tile[c_l][tx] = F[(size_t)(c0 + c_l) * N_DIM + i0 + tx] * scale[tx];
        }
        __syncthreads();
        #pragma unroll
        for (int half = 0; half < 2; ++half) {
            int il = i_l + half * 32;
            __align__(16) ushort pack[8];
            #pragma unroll
            for (int j = 0; j < 8; ++j)
                pack[j] = f2bf(tile[c_off + j][il]);
            *(uint4*)&T[(size_t)(i0 + il) * C_DIM + c0 + c_off] = *(const uint4*)pack;
        }
        __syncthreads();
    }
}

// ---------------------------------------------------------------------------
// Fused GEMM + row-max, round 7: 4-phase K-tile schedule, SINGLE 64KB buffer.
//   256x256 block tile, BK=64, 512 thr / 8 waves (2M x 4N), per-wave 128x64
//   (8x4 frags, 128 acc VGPRs).  LDS = A 32KB + B 32KB = 64 KB (no dbuf).
//
// Regions are read in exactly ONE phase per K-tile (frags held in regs), so
// tile j+1's region X is staged IN PLACE in the phase after X's last read:
//   p0: read A m0-3 (R0, 8 ds) + B n0-1 (S0, 4 ds) | no stage      | 16 MFMA
//   p1: read B n2-3 (S1, 4 ds)                     | stage R0,S0 x4| 16 MFMA
//   p2: read A m4-7 (R1, 8 ds)                     | stage S1   x2 | 16 MFMA
//   p3: (frags held)                               | stage R1   x2 | 16 MFMA
// Phase: {ds_read; stage; s_barrier; lgkmcnt(0); sched_barrier(0);
//         setprio(1); 16 MFMA; setprio(0); [vmcnt(N)]; s_barrier}.
// vmcnt precedes the tail barrier: vmcnt is per-wave, consumption is
// cross-wave; the barrier publishes the landing block-wide.
//
// FIFO ledger (steady): entry [S1(2),R1(2)] -> p0 tail vmcnt(2) certifies S1
// -> p1 +4 = 6, tail vmcnt(4) certifies R1 -> p2 +2 = 6, no wait -> p3 +2
// = 8, tail vmcnt(4) certifies next R0,S0.  Never drains below 2 in-loop.
// WAR: stage targets a region whose reads were drained by that phase's own
// lgkmcnt(0)s and published by the preceding tail barrier.  Final H (no
// stage): waits (2,0,-) -> 0 outstanding at endpgm.
//
// LDS layout (ushort elems):
//   A: natural row r (0..255) at r*64; chunk q at qpos=q^(r&7) (16B chunks).
//   B: phys row p at p*64, same XOR; p<128: logical n=(p>>5)*64+(p&31)
//      (wn first-halves), p>=128: n=((p-128)>>5)*64+32+(p&31) (second).
//   Staging src (rule 21, pre-swizzled global): thread t -> phys row
//   base+(t>>3), content chunk (t&7)^((t>>3)&7); base%64==0 keeps it valid
//   for all issues.  2-way bank aliasing on frag ds_reads (free, m136).
// ---------------------------------------------------------------------------
__device__ __forceinline__ f32x4 mfma16(short8 a, short8 b, f32x4 c) {
    return __builtin_amdgcn_mfma_f32_16x16x32_bf16(a, b, c, 0, 0, 0);
}

template<bool STAGE, int W0, int W1, int W3>
__device__ __forceinline__ void half_iter(
    ushort* As, ushort* Bs,
    const ushort* agA, const ushort* bgB,    // per-thread pre-swizzled src
    int ktn,                                 // K-tile being staged (if STAGE)
    int ldst, int abase, int bbase, int aq0, int aq1,
    f32x4 (&acc)[8][4])
{
    const int ko = ktn * 64;
    short8 a03[4][2], a47[4][2], b01[2][2], b23[2][2];

    // ---------------- phase 0: C(m0-3, n0-1); reads R0+S0 ----------------
    #pragma unroll
    for (int mt = 0; mt < 4; ++mt) {
        a03[mt][0] = *(const short8*)(As + abase + mt * 1024 + aq0);
        a03[mt][1] = *(const short8*)(As + abase + mt * 1024 + aq1);
    }
    #pragma unroll
    for (int nt = 0; nt < 2; ++nt) {
        b01[nt][0] = *(const short8*)(Bs + bbase + nt * 1024 + aq0);
        b01[nt][1] = *(const short8*)(Bs + bbase + nt * 1024 + aq1);
    }
    __builtin_amdgcn_s_barrier();
    asm volatile("s_waitcnt lgkmcnt(0)" ::: "memory");
    __builtin_amdgcn_sched_barrier(0);
    __builtin_amdgcn_s_setprio(1);
    #pragma unroll
    for (int mt = 0; mt < 4; ++mt)
        #pragma unroll
        for (int nt = 0; nt < 2; ++nt) {
            acc[mt][nt] = mfma16(a03[mt][0], b01[nt][0], acc[mt][nt]);
            acc[mt][nt] = mfma16(a03[mt][1], b01[nt][1], acc[mt][nt]);
        }
    __builtin_amdgcn_s_setprio(0);
    wait_vmcnt<W0>();                         // certify S1 (read next phase)
    __builtin_amdgcn_s_barrier();

    // ------- phase 1: C(m0-3, n2-3); reads S1; stages next R0,S0 -------
    #pragma unroll
    for (int nt = 0; nt < 2; ++nt) {
        b23[nt][0] = *(const short8*)(Bs + 8192 + bbase + nt * 1024 + aq0);
        b23[nt][1] = *(const short8*)(Bs + 8192 + bbase + nt * 1024 + aq1);
    }
    if constexpr (STAGE) {   // R0: A rows {0-63,128-191}; S0: B phys 0-127
        async_ld16(agA + ko,                 As + ldst);
        async_ld16(agA + ko + 128 * C_DIM,   As + 8192 + ldst);
        async_ld16(bgB + ko,                 Bs + ldst);
        async_ld16(bgB + ko + 128 * C_DIM,   Bs + 4096 + ldst);
    }
    __builtin_amdgcn_s_barrier();
    asm volatile("s_waitcnt lgkmcnt(0)" ::: "memory");
    __builtin_amdgcn_sched_barrier(0);
    __builtin_amdgcn_s_setprio(1);
    #pragma unroll
    for (int mt = 0; mt < 4; ++mt)
        #pragma unroll
        for (int nt = 0; nt < 2; ++nt) {
            acc[mt][2 + nt] = mfma16(a03[mt][0], b23[nt][0], acc[mt][2 + nt]);
            acc[mt][2 + nt] = mfma16(a03[mt][1], b23[nt][1], acc[mt][2 + nt]);
        }
    __builtin_amdgcn_s_setprio(0);
    wait_vmcnt<W1>();                         // certify R1 (read next phase)
    __builtin_amdgcn_s_barrier();

    // ------- phase 2: C(m4-7, n0-1); reads R1; stages next S1 -------
    #pragma unroll
    for (int mt = 0; mt < 4; ++mt) {
        a47[mt][0] = *(const short8*)(As + 4096 + abase + mt * 1024 + aq0);
        a47[mt][1] = *(const short8*)(As + 4096 + abase + mt * 1024 + aq1);
    }
    if constexpr (STAGE) {   // S1: B phys 128-255
        async_ld16(bgB + ko + 32 * C_DIM,    Bs + 8192 + ldst);
        async_ld16(bgB + ko + 160 * C_DIM,   Bs + 12288 + ldst);
    }
    __builtin_amdgcn_s_barrier();
    asm volatile("s_waitcnt lgkmcnt(0)" ::: "memory");
    __builtin_amdgcn_sched_barrier(0);
    __builtin_amdgcn_s_setprio(1);
    #pragma unroll
    for (int mt = 0; mt < 4; ++mt)
        #pragma unroll
        for (int nt = 0; nt < 2; ++nt) {
            acc[4 + mt][nt] = mfma16(a47[mt][0], b01[nt][0], acc[4 + mt][nt]);
            acc[4 + mt][nt] = mfma16(a47[mt][1], b01[nt][1], acc[4 + mt][nt]);
        }
    __builtin_amdgcn_s_setprio(0);
    __builtin_amdgcn_s_barrier();             // p3 reads nothing: no wait

    // ------- phase 3: C(m4-7, n2-3); stages next R1 -------
    if constexpr (STAGE) {   // R1: A rows {64-127,192-255}
        async_ld16(agA + ko + 64 * C_DIM,    As + 4096 + ldst);
        async_ld16(agA + ko + 192 * C_DIM,   As + 12288 + ldst);
    }
    __builtin_amdgcn_s_barrier();
    __builtin_amdgcn_s_setprio(1);
    #pragma unroll
    for (int mt = 0; mt < 4; ++mt)
        #pragma unroll
        for (int nt = 0; nt < 2; ++nt) {
            acc[4 + mt][2 + nt] = mfma16(a47[mt][0], b23[nt][0], acc[4 + mt][2 + nt]);
            acc[4 + mt][2 + nt] = mfma16(a47[mt][1], b23[nt][1], acc[4 + mt][2 + nt]);
        }
    __builtin_amdgcn_s_setprio(0);
    wait_vmcnt<W3>();                         // certify next R0,S0
    __builtin_amdgcn_s_barrier();
}

__global__ __launch_bounds__(512, 2) void gemm_rowmax(const ushort* __restrict__ A,
                                                      const ushort* __restrict__ B,
                                                      unsigned* __restrict__ rowkey) {
    __shared__ __align__(16) ushort As[16384];   // 32 KB
    __shared__ __align__(16) ushort Bs[16384];   // 32 KB -> 64 KB total

    const int t    = threadIdx.x;
    const int lane = t & 63;
    const int w    = t >> 6;          // 0..7
    const int wm   = w >> 2;          // 0..1  (128-row half)
    const int wn   = w & 3;           // 0..3  (64-col quarter)

    // XCD-aware mapping (4096 blocks, %8==0): each XCD owns an 8-tile n-slice
    // (2048 cols of B = 3MB in its L2); n fastest for A-panel L2 reuse.
    const int bid   = blockIdx.x;
    const int xcd   = bid & 7;
    const int local = bid >> 3;                       // 0..511
    const int m0    = (local >> 3) * 256;             // 64 m-tiles
    const int n0    = (xcd * 8 + (local & 7)) * 256;  // 64 n-tiles

    f32x4 acc[8][4];
    #pragma unroll
    for (int i = 0; i < 8; ++i)
        #pragma unroll
        for (int j = 0; j < 4; ++j)
            acc[i][j] = (f32x4){0.f, 0.f, 0.f, 0.f};

    // --- staging sources (pre-swizzled global): thread t covers phys row
    // base+(t>>3) (base%64==0), phys chunk t&7, content chunk (t&7)^((t>>3)&7)
    const int srow = t >> 3;                           // 0..63
    const int schk = ((t & 7) ^ (srow & 7)) * 8;       // element offset
    const ushort* agA = A + (size_t)(m0 + srow) * C_DIM + schk;
    const int brow = ((t >> 8) & 1) * 64 + (srow & 31);
    const ushort* bgB = B + (size_t)(n0 + brow) * C_DIM + schk;
    const int ldst = t * 8;                            // linear LDS dest

    // --- fragment read addressing (phys row &7 == lane&7 on both sides) ---
    const int aq0   = ((lane >> 4) ^ (lane & 7)) * 8;
    const int aq1   = (((lane >> 4) + 4) ^ (lane & 7)) * 8;
    const int abase = wm * 8192 + (lane & 15) * 64;
    const int bbase = wn * 2048 + (lane & 15) * 64;

    // --- prologue: stage tile 0 in FIFO order R0,S0,S1,R1; certify R0,S0 ---
    async_ld16(agA,                 As + ldst);
    async_ld16(agA + 128 * C_DIM,   As + 8192 + ldst);
    async_ld16(bgB,                 Bs + ldst);
    async_ld16(bgB + 128 * C_DIM,   Bs + 4096 + ldst);
    async_ld16(bgB + 32 * C_DIM,    Bs + 8192 + ldst);
    async_ld16(bgB + 160 * C_DIM,   Bs + 12288 + ldst);
    async_ld16(agA + 64 * C_DIM,    As + 4096 + ldst);
    async_ld16(agA + 192 * C_DIM,   As + 12288 + ldst);
    wait_vmcnt<4>();
    __builtin_amdgcn_s_barrier();

    // --- 12 K-tiles: H_0..H_10 stage tiles 1..11; H_11 drains ---
    #pragma unroll 1
    for (int j = 0; j < 11; ++j)
        half_iter<true, 2, 4, 4>(As, Bs, agA, bgB, j + 1,
                                 ldst, abase, bbase, aq0, aq1, acc);
    half_iter<false, 2, 0, -1>(As, Bs, agA, bgB, 0,
                               ldst, abase, bbase, aq0, aq1, acc);

    // --- epilogue: per-row max over this wave's 64 cols; merge via atomicMax.
    // C/D layout: col = lane&15, row = (lane>>4)*4 + reg.
    #pragma unroll
    for (int mt = 0; mt < 8; ++mt) {
        #pragma unroll
        for (int reg = 0; reg < 4; ++reg) {
            float v = fmaxf(fmaxf(acc[mt][0][reg], acc[mt][1][reg]),
                            fmaxf(acc[mt][2][reg], acc[mt][3][reg]));
            #pragma unroll
            for (int off = 1; off < 16; off <<= 1)
                v = fmaxf(v, __shfl_xor(v, off, 64));
            if ((lane & 15) == 0) {
                int m = m0 + wm * 128 + mt * 16 + (lane >> 4) * 4 + reg;
                unsigned u = __float_as_uint(v);
                u = (u & 0x80000000u) ? ~u : (u | 0x80000000u);  // order-preserving
                atomicMax(&rowkey[m], u);
            }
        }
    }
}

// ---------------------------------------------------------------------------
// Final: loss = 1 - mean(rowmax)
// ---------------------------------------------------------------------------
__global__ __launch_bounds__(1024) void finalize(const unsigned* __restrict__ rowkey,
                                                 float* __restrict__ out) {
    const int t = threadIdx.x;
    float s = 0.f;
    for (int i = t; i < N_DIM; i += 1024) {
        unsigned u = rowkey[i];
        float f = (u & 0x80000000u) ? __uint_as_float(u ^ 0x80000000u)
                                    : __uint_as_float(~u);
        s += f;
    }
    #pragma unroll
    for (int off = 32; off >= 1; off >>= 1)
        s += __shfl_down(s, off, 64);
    __shared__ float part[16];
    if ((t & 63) == 0) part[t >> 6] = s;
    __syncthreads();
    if (t == 0) {
        float tot = 0.f;
        #pragma unroll
        for (int i = 0; i < 16; ++i) tot += part[i];
        out[0] = 1.0f - tot * (1.0f / (float)N_DIM);
    }
}

extern "C" void kernel_launch(void* const* d_in, const int* in_sizes, int n_in,
                              void* d_out, int out_size, void* d_ws, size_t ws_size,
                              hipStream_t stream) {
    const float* F_r = (const float*)d_in[0];
    const float* F_s = (const float*)d_in[1];

    ushort*   Rt     = (ushort*)d_ws;                       // 16384 x 768 bf16
    ushort*   St     = Rt + (size_t)N_DIM * C_DIM;          // 16384 x 768 bf16
    unsigned* rowkey = (unsigned*)(St + (size_t)N_DIM * C_DIM);  // 16384 u32
    float*    out    = (float*)d_out;

    hipLaunchKernelGGL(norm_tr, dim3(N_DIM / 64, 2), dim3(256), 0, stream,
                       F_r, Rt, F_s, St);
    hipMemsetAsync(rowkey, 0, N_DIM * sizeof(unsigned), stream);
    hipLaunchKernelGGL(gemm_rowmax, dim3((N_DIM / 256) * (N_DIM / 256)), dim3(512),
                       0, stream, Rt, St, rowkey);
    hipLaunchKernelGGL(finalize, dim3(1), dim3(1024), 0, stream, rowkey, out);
}

// Round 5
// 735.088 us; speedup vs baseline: 1.1166x; 1.1166x over previous
//
#include <hip/hip_runtime.h>
#include <cstdint>
#include <cstddef>

#define C_DIM 768
#define N_DIM 16384

typedef __attribute__((ext_vector_type(8))) short short8;   // 8 bf16 = 4 VGPRs
typedef __attribute__((ext_vector_type(4))) float f32x4;

__device__ __forceinline__ ushort f2bf(float f) {
    uint32_t u = __float_as_uint(f);
    uint32_t r = 0x7fffu + ((u >> 16) & 1u);   // round-to-nearest-even
    return (ushort)((u + r) >> 16);
}

__device__ __forceinline__ void async_ld16(const void* g, void* l) {
    __builtin_amdgcn_global_load_lds(
        (__attribute__((address_space(1))) void*)g,
        (__attribute__((address_space(3))) void*)l,
        16, 0, 0);
}

// ---------------------------------------------------------------------------
// Normalize columns of F (C_DIM x N_DIM) and write transposed bf16:
// T[i][c] = F[c][i] / max(||col_i||, eps).  blockIdx.y selects the input.
// (verified; unchanged)
// ---------------------------------------------------------------------------
__global__ __launch_bounds__(256) void norm_tr(const float* __restrict__ F0,
                                               ushort* __restrict__ T0,
                                               const float* __restrict__ F1,
                                               ushort* __restrict__ T1) {
    const float*  F = blockIdx.y ? F1 : F0;
    ushort*       T = blockIdx.y ? T1 : T0;
    const int i0 = blockIdx.x * 64;
    const int t  = threadIdx.x;
    const int tx = t & 63;
    const int ty = t >> 6;

    float ss = 0.f;
    for (int c = ty; c < C_DIM; c += 4) {
        float v = F[(size_t)c * N_DIM + i0 + tx];
        ss += v * v;
    }
    __shared__ float red[4][64];
    __shared__ float scale[64];
    red[ty][tx] = ss;
    __syncthreads();
    if (t < 64) {
        float s = red[0][t] + red[1][t] + red[2][t] + red[3][t];
        float n = sqrtf(s);
        scale[t] = 1.0f / fmaxf(n, 1e-12f);
    }
    __syncthreads();

    __shared__ float tile[64][65];
    const int i_l   = t >> 3;
    const int c_off = (t & 7) * 8;
    for (int c0 = 0; c0 < C_DIM; c0 += 64) {
        #pragma unroll
        for (int rr = 0; rr < 16; ++rr) {
            int c_l = rr * 4 + ty;
            tile[c_l][tx] = F[(size_t)(c0 + c_l) * N_DIM + i0 + tx] * scale[tx];
        }
        __syncthreads();
        #pragma unroll
        for (int half = 0; half < 2; ++half) {
            int il = i_l + half * 32;
            __align__(16) ushort pack[8];
            #pragma unroll
            for (int j = 0; j < 8; ++j)
                pack[j] = f2bf(tile[c_off + j][il]);
            *(uint4*)&T[(size_t)(i0 + il) * C_DIM + c0 + c_off] = *(const uint4*)pack;
        }
        __syncthreads();
    }
}

// ---------------------------------------------------------------------------
// Fused GEMM + row-max, round 8: r4's verified layout (256x256 tile, BK=64,
// 512 thr / 8 waves, 64 KB single-buffer in-place staging) with the ds_read
// pipeline SHIFTED ONE PHASE EARLY.  r4's measured failure: lgkmcnt(0) +
// 2 barriers per phase serialized LDS pipe and MFMA pipe (MfmaUtil 27%).
// Now each phase issues NEXT phase's fragment reads, then MFMAs on regs
// loaded LAST phase; compiler emits counted lgkm waits (FIFO: needed loads
// are always older than this phase's issues).  One barrier per phase.
//
//   p0: read b23(4)            | no stage    | MFMA a03*b01 | vmcnt(0) bar
//   p1: read a47(8)            | stage R0,S0 | MFMA a03*b23 |          bar
//   p2: -                      | stage S1    | MFMA a47*b01 | vmcnt(2) bar
//   p3: read a03',b01' (12)    | stage R1    | MFMA a47*b23 | vmcnt(2) bar
//
// vmcnt FIFO ledger (2 loads/region): entering p0 outstanding=[R1_j(2)];
// p0 vmcnt(0) retires R1 (issued 1.25 tiles back - landed; certifies p1's
// a47 reads).  p1 +4 -> [R0S0(4)]; p2 +2 -> [R0S0(4),S1(2)], vmcnt(2)
// retires R0,S0 (certifies p3's a03',b01' reads).  p3 +2 -> [S1(2),R1(2)],
// vmcnt(2) retires S1 (certifies next p0's b23 reads).  Invariant holds.
// Anti-hazards: region reads retire before the barrier preceding its
// restage: a03/b01 reads (p3-prev) retire before p0's MFMA (compiler wait)
// -> before p0-tail bar -> stage at p1 OK; b23 (p0) before p1-tail -> stage
// S1 at p2 OK; a47 (p1) before p2-tail -> stage R1 at p3 OK.
// Register clobbers: a03/b01 re-read at p3 after last use (p1/p2); b23
// re-read at p0' after last use p3; a47 at p1' after p3.  MFMA order per
// acc element identical to r4 (bitwise-same accumulation).
// ---------------------------------------------------------------------------
__device__ __forceinline__ f32x4 mfma16(short8 a, short8 b, f32x4 c) {
    return __builtin_amdgcn_mfma_f32_16x16x32_bf16(a, b, c, 0, 0, 0);
}

template<bool STAGE, bool READNEXT>
__device__ __forceinline__ void half_iter(
    ushort* As, ushort* Bs,
    const ushort* agA, const ushort* bgB,    // per-thread pre-swizzled src
    int ktn,                                 // K-tile being staged (if STAGE)
    int ldst, int abase, int bbase, int aq0, int aq1,
    short8 (&a03)[4][2], short8 (&a47)[4][2],
    short8 (&b01)[2][2], short8 (&b23)[2][2],
    f32x4 (&acc)[8][4])
{
    const int ko = ktn * 64;

    // ---- p0: MFMA a03*b01 ; read b23 (S1_j, certified at p3-prev) ----
    #pragma unroll
    for (int nt = 0; nt < 2; ++nt) {
        b23[nt][0] = *(const short8*)(Bs + 8192 + bbase + nt * 1024 + aq0);
        b23[nt][1] = *(const short8*)(Bs + 8192 + bbase + nt * 1024 + aq1);
    }
    __builtin_amdgcn_sched_barrier(0);
    __builtin_amdgcn_s_setprio(1);
    #pragma unroll
    for (int mt = 0; mt < 4; ++mt)
        #pragma unroll
        for (int nt = 0; nt < 2; ++nt) {
            acc[mt][nt] = mfma16(a03[mt][0], b01[nt][0], acc[mt][nt]);
            acc[mt][nt] = mfma16(a03[mt][1], b01[nt][1], acc[mt][nt]);
        }
    __builtin_amdgcn_s_setprio(0);
    asm volatile("s_waitcnt vmcnt(0)" ::: "memory");   // R1_j (issued p3-prev)
    __builtin_amdgcn_s_barrier();
    __builtin_amdgcn_sched_barrier(0);

    // ---- p1: MFMA a03*b23 ; read a47 (R1_j) ; stage R0,S0 of tile j+1 ----
    #pragma unroll
    for (int mt = 0; mt < 4; ++mt) {
        a47[mt][0] = *(const short8*)(As + 4096 + abase + mt * 1024 + aq0);
        a47[mt][1] = *(const short8*)(As + 4096 + abase + mt * 1024 + aq1);
    }
    if constexpr (STAGE) {
        async_ld16(agA + ko,                 As + ldst);
        async_ld16(agA + ko + 128 * C_DIM,   As + 8192 + ldst);
        async_ld16(bgB + ko,                 Bs + ldst);
        async_ld16(bgB + ko + 128 * C_DIM,   Bs + 4096 + ldst);
    }
    __builtin_amdgcn_sched_barrier(0);
    __builtin_amdgcn_s_setprio(1);
    #pragma unroll
    for (int mt = 0; mt < 4; ++mt)
        #pragma unroll
        for (int nt = 0; nt < 2; ++nt) {
            acc[mt][2 + nt] = mfma16(a03[mt][0], b23[nt][0], acc[mt][2 + nt]);
            acc[mt][2 + nt] = mfma16(a03[mt][1], b23[nt][1], acc[mt][2 + nt]);
        }
    __builtin_amdgcn_s_setprio(0);
    __builtin_amdgcn_s_barrier();
    __builtin_amdgcn_sched_barrier(0);

    // ---- p2: MFMA a47*b01 ; stage S1 of tile j+1 ----
    if constexpr (STAGE) {
        async_ld16(bgB + ko + 32 * C_DIM,    Bs + 8192 + ldst);
        async_ld16(bgB + ko + 160 * C_DIM,   Bs + 12288 + ldst);
    }
    __builtin_amdgcn_sched_barrier(0);
    __builtin_amdgcn_s_setprio(1);
    #pragma unroll
    for (int mt = 0; mt < 4; ++mt)
        #pragma unroll
        for (int nt = 0; nt < 2; ++nt) {
            acc[4 + mt][nt] = mfma16(a47[mt][0], b01[nt][0], acc[4 + mt][nt]);
            acc[4 + mt][nt] = mfma16(a47[mt][1], b01[nt][1], acc[4 + mt][nt]);
        }
    __builtin_amdgcn_s_setprio(0);
    if constexpr (STAGE)
        asm volatile("s_waitcnt vmcnt(2)" ::: "memory");   // R0,S0 certified
    __builtin_amdgcn_s_barrier();
    __builtin_amdgcn_sched_barrier(0);

    // ---- p3: MFMA a47*b23 ; read next a03,b01 (R0,S0) ; stage R1 ----
    if constexpr (READNEXT) {
        #pragma unroll
        for (int mt = 0; mt < 4; ++mt) {
            a03[mt][0] = *(const short8*)(As + abase + mt * 1024 + aq0);
            a03[mt][1] = *(const short8*)(As + abase + mt * 1024 + aq1);
        }
        #pragma unroll
        for (int nt = 0; nt < 2; ++nt) {
            b01[nt][0] = *(const short8*)(Bs + bbase + nt * 1024 + aq0);
            b01[nt][1] = *(const short8*)(Bs + bbase + nt * 1024 + aq1);
        }
    }
    if constexpr (STAGE) {
        async_ld16(agA + ko + 64 * C_DIM,    As + 4096 + ldst);
        async_ld16(agA + ko + 192 * C_DIM,   As + 12288 + ldst);
    }
    __builtin_amdgcn_sched_barrier(0);
    __builtin_amdgcn_s_setprio(1);
    #pragma unroll
    for (int mt = 0; mt < 4; ++mt)
        #pragma unroll
        for (int nt = 0; nt < 2; ++nt) {
            acc[4 + mt][2 + nt] = mfma16(a47[mt][0], b23[nt][0], acc[4 + mt][2 + nt]);
            acc[4 + mt][2 + nt] = mfma16(a47[mt][1], b23[nt][1], acc[4 + mt][2 + nt]);
        }
    __builtin_amdgcn_s_setprio(0);
    if constexpr (STAGE)
        asm volatile("s_waitcnt vmcnt(2)" ::: "memory");   // S1 certified
    __builtin_amdgcn_s_barrier();
    __builtin_amdgcn_sched_barrier(0);
}

__global__ __launch_bounds__(512, 2) void gemm_rowmax(const ushort* __restrict__ A,
                                                      const ushort* __restrict__ B,
                                                      unsigned* __restrict__ rowkey) {
    __shared__ __align__(16) ushort As[16384];   // 32 KB
    __shared__ __align__(16) ushort Bs[16384];   // 32 KB -> 64 KB total

    const int t    = threadIdx.x;
    const int lane = t & 63;
    const int w    = t >> 6;          // 0..7
    const int wm   = w >> 2;          // 0..1  (128-row half)
    const int wn   = w & 3;           // 0..3  (64-col quarter)

    // XCD-aware mapping (4096 blocks, %8==0): each XCD owns an 8-tile n-slice
    // (2048 cols of B = 3MB in its L2); n fastest for A-panel L2 reuse.
    const int bid   = blockIdx.x;
    const int xcd   = bid & 7;
    const int local = bid >> 3;                       // 0..511
    const int m0    = (local >> 3) * 256;             // 64 m-tiles
    const int n0    = (xcd * 8 + (local & 7)) * 256;  // 64 n-tiles

    f32x4 acc[8][4];
    #pragma unroll
    for (int i = 0; i < 8; ++i)
        #pragma unroll
        for (int j = 0; j < 4; ++j)
            acc[i][j] = (f32x4){0.f, 0.f, 0.f, 0.f};

    // --- staging sources (pre-swizzled global): thread t covers phys row
    // base+(t>>3) (base%64==0), phys chunk t&7, content chunk (t&7)^((t>>3)&7)
    const int srow = t >> 3;                           // 0..63
    const int schk = ((t & 7) ^ (srow & 7)) * 8;       // element offset
    const ushort* agA = A + (size_t)(m0 + srow) * C_DIM + schk;
    const int brow = ((t >> 8) & 1) * 64 + (srow & 31);
    const ushort* bgB = B + (size_t)(n0 + brow) * C_DIM + schk;
    const int ldst = t * 8;                            // linear LDS dest

    // --- fragment read addressing (phys row &7 == lane&7 on both sides) ---
    const int aq0   = ((lane >> 4) ^ (lane & 7)) * 8;
    const int aq1   = (((lane >> 4) + 4) ^ (lane & 7)) * 8;
    const int abase = wm * 8192 + (lane & 15) * 64;
    const int bbase = wn * 2048 + (lane & 15) * 64;

    short8 a03[4][2], a47[4][2], b01[2][2], b23[2][2];

    // --- prologue: stage tile 0 in FIFO order R0,S0,S1,R1 ---
    async_ld16(agA,                 As + ldst);
    async_ld16(agA + 128 * C_DIM,   As + 8192 + ldst);
    async_ld16(bgB,                 Bs + ldst);
    async_ld16(bgB + 128 * C_DIM,   Bs + 4096 + ldst);
    async_ld16(bgB + 32 * C_DIM,    Bs + 8192 + ldst);
    async_ld16(bgB + 160 * C_DIM,   Bs + 12288 + ldst);
    async_ld16(agA + 64 * C_DIM,    As + 4096 + ldst);
    async_ld16(agA + 192 * C_DIM,   As + 12288 + ldst);
    asm volatile("s_waitcnt vmcnt(4)" ::: "memory");   // R0,S0 landed
    __builtin_amdgcn_s_barrier();
    __builtin_amdgcn_sched_barrier(0);

    // prologue fragment reads for tile 0 / phase 0
    #pragma unroll
    for (int mt = 0; mt < 4; ++mt) {
        a03[mt][0] = *(const short8*)(As + abase + mt * 1024 + aq0);
        a03[mt][1] = *(const short8*)(As + abase + mt * 1024 + aq1);
    }
    #pragma unroll
    for (int nt = 0; nt < 2; ++nt) {
        b01[nt][0] = *(const short8*)(Bs + bbase + nt * 1024 + aq0);
        b01[nt][1] = *(const short8*)(Bs + bbase + nt * 1024 + aq1);
    }
    asm volatile("s_waitcnt vmcnt(2)" ::: "memory");   // S1 landed; R1 in flight
    __builtin_amdgcn_s_barrier();
    __builtin_amdgcn_sched_barrier(0);

    // --- 12 K-tiles: tiles 0..10 stage tile j+1; tile 11 drains ---
    #pragma unroll 1
    for (int j = 0; j < 11; ++j)
        half_iter<true, true>(As, Bs, agA, bgB, j + 1,
                              ldst, abase, bbase, aq0, aq1,
                              a03, a47, b01, b23, acc);
    half_iter<false, false>(As, Bs, agA, bgB, 0,
                            ldst, abase, bbase, aq0, aq1,
                            a03, a47, b01, b23, acc);

    // --- epilogue: per-row max over this wave's 64 cols; merge via atomicMax.
    // C/D layout: col = lane&15, row = (lane>>4)*4 + reg.
    #pragma unroll
    for (int mt = 0; mt < 8; ++mt) {
        #pragma unroll
        for (int reg = 0; reg < 4; ++reg) {
            float v = fmaxf(fmaxf(acc[mt][0][reg], acc[mt][1][reg]),
                            fmaxf(acc[mt][2][reg], acc[mt][3][reg]));
            #pragma unroll
            for (int off = 1; off < 16; off <<= 1)
                v = fmaxf(v, __shfl_xor(v, off, 64));
            if ((lane & 15) == 0) {
                int m = m0 + wm * 128 + mt * 16 + (lane >> 4) * 4 + reg;
                unsigned u = __float_as_uint(v);
                u = (u & 0x80000000u) ? ~u : (u | 0x80000000u);  // order-preserving
                atomicMax(&rowkey[m], u);
            }
        }
    }
}

// ---------------------------------------------------------------------------
// Final: loss = 1 - mean(rowmax)
// ---------------------------------------------------------------------------
__global__ __launch_bounds__(1024) void finalize(const unsigned* __restrict__ rowkey,
                                                 float* __restrict__ out) {
    const int t = threadIdx.x;
    float s = 0.f;
    for (int i = t; i < N_DIM; i += 1024) {
        unsigned u = rowkey[i];
        float f = (u & 0x80000000u) ? __uint_as_float(u ^ 0x80000000u)
                                    : __uint_as_float(~u);
        s += f;
    }
    #pragma unroll
    for (int off = 32; off >= 1; off >>= 1)
        s += __shfl_down(s, off, 64);
    __shared__ float part[16];
    if ((t & 63) == 0) part[t >> 6] = s;
    __syncthreads();
    if (t == 0) {
        float tot = 0.f;
        #pragma unroll
        for (int i = 0; i < 16; ++i) tot += part[i];
        out[0] = 1.0f - tot * (1.0f / (float)N_DIM);
    }
}

extern "C" void kernel_launch(void* const* d_in, const int* in_sizes, int n_in,
                              void* d_out, int out_size, void* d_ws, size_t ws_size,
                              hipStream_t stream) {
    const float* F_r = (const float*)d_in[0];
    const float* F_s = (const float*)d_in[1];

    ushort*   Rt     = (ushort*)d_ws;                       // 16384 x 768 bf16
    ushort*   St     = Rt + (size_t)N_DIM * C_DIM;          // 16384 x 768 bf16
    unsigned* rowkey = (unsigned*)(St + (size_t)N_DIM * C_DIM);  // 16384 u32
    float*    out    = (float*)d_out;

    hipLaunchKernelGGL(norm_tr, dim3(N_DIM / 64, 2), dim3(256), 0, stream,
                       F_r, Rt, F_s, St);
    hipMemsetAsync(rowkey, 0, N_DIM * sizeof(unsigned), stream);
    hipLaunchKernelGGL(gemm_rowmax, dim3((N_DIM / 256) * (N_DIM / 256)), dim3(512),
                       0, stream, Rt, St, rowkey);
    hipLaunchKernelGGL(finalize, dim3(1), dim3(1024), 0, stream, rowkey, out);
}

// Round 6
// 730.613 us; speedup vs baseline: 1.1235x; 1.0061x over previous
//
#include <hip/hip_runtime.h>
#include <cstdint>
#include <cstddef>

#define C_DIM 768
#define N_DIM 16384

typedef __attribute__((ext_vector_type(8))) short short8;   // 8 bf16 = 4 VGPRs
typedef __attribute__((ext_vector_type(4))) float f32x4;

__device__ __forceinline__ ushort f2bf(float f) {
    uint32_t u = __float_as_uint(f);
    uint32_t r = 0x7fffu + ((u >> 16) & 1u);   // round-to-nearest-even
    return (ushort)((u + r) >> 16);
}

__device__ __forceinline__ void async_ld16(const void* g, void* l) {
    __builtin_amdgcn_global_load_lds(
        (__attribute__((address_space(1))) void*)g,
        (__attribute__((address_space(3))) void*)l,
        16, 0, 0);
}

// ---------------------------------------------------------------------------
// Normalize columns of F (C_DIM x N_DIM) and write transposed bf16:
// T[i][c] = F[c][i] / max(||col_i||, eps).  blockIdx.y selects the input.
// (verified; unchanged)
// ---------------------------------------------------------------------------
__global__ __launch_bounds__(256) void norm_tr(const float* __restrict__ F0,
                                               ushort* __restrict__ T0,
                                               const float* __restrict__ F1,
                                               ushort* __restrict__ T1) {
    const float*  F = blockIdx.y ? F1 : F0;
    ushort*       T = blockIdx.y ? T1 : T0;
    const int i0 = blockIdx.x * 64;
    const int t  = threadIdx.x;
    const int tx = t & 63;
    const int ty = t >> 6;

    float ss = 0.f;
    for (int c = ty; c < C_DIM; c += 4) {
        float v = F[(size_t)c * N_DIM + i0 + tx];
        ss += v * v;
    }
    __shared__ float red[4][64];
    __shared__ float scale[64];
    red[ty][tx] = ss;
    __syncthreads();
    if (t < 64) {
        float s = red[0][t] + red[1][t] + red[2][t] + red[3][t];
        float n = sqrtf(s);
        scale[t] = 1.0f / fmaxf(n, 1e-12f);
    }
    __syncthreads();

    __shared__ float tile[64][65];
    const int i_l   = t >> 3;
    const int c_off = (t & 7) * 8;
    for (int c0 = 0; c0 < C_DIM; c0 += 64) {
        #pragma unroll
        for (int rr = 0; rr < 16; ++rr) {
            int c_l = rr * 4 + ty;
            tile[c_l][tx] = F[(size_t)(c0 + c_l) * N_DIM + i0 + tx] * scale[tx];
        }
        __syncthreads();
        #pragma unroll
        for (int half = 0; half < 2; ++half) {
            int il = i_l + half * 32;
            __align__(16) ushort pack[8];
            #pragma unroll
            for (int j = 0; j < 8; ++j)
                pack[j] = f2bf(tile[c_off + j][il]);
            *(uint4*)&T[(size_t)(i0 + il) * C_DIM + c0 + c_off] = *(const uint4*)pack;
        }
        __syncthreads();
    }
}

// ---------------------------------------------------------------------------
// Fused GEMM + row-max, round 9: r2's verified loop skeleton + swizzle,
// scaled to a 256x256 block tile with 1024 threads / 16 waves (4M x 4N),
// BK=32, TRUE double-buffer at exactly 64 KB LDS.
//
// Why (counters r2/r4/r5): all schedules pinned at 27-33% MfmaUtil.
//   r2 (14 waves/CU) beat r4/r5 (2 waves/SIMD) despite "better" phase
//   engineering -> occupancy (implicit wave overlap, m114) is the binding
//   lever; >64KB LDS (the m201 dbuf template) hard-fails this harness.
// This config: 4 waves/SIMD (acc 64 f32 -> ~128 total regs, same per-wave
// shape that compiled to 64 VGPR + 64 AGPR in r0) AND half the staged
// bytes/FLOP of r2 (32 KB per 4.2 MFLOP vs 24 KB per 2.1 MFLOP) AND
// 0.5 ds_read/MFMA with a full-iteration stage->read slack via dbuf.
// Per-CU per K-tile: LDS reads 128x12=1536 cyc vs MFMA 256x4.85=1241 cyc
// -> overlap ceiling ~67% MfmaUtil (vs 30% measured in r5).
//
// Loop (r2-verified skeleton): stage k+1 into buf^1 FIRST (2 loads ride
// across the barrier); vmcnt(2) waits only tile k (issued a full iter ago);
// raw s_barrier publishes block-wide; 8 ds_read; 16 MFMA (setprio);
// lgkmcnt(0)+barrier protects the stage-after-read WAR.  Last iter peeled
// (vmcnt(0), no stage) -> nothing outstanding at endpgm.
//
// Addressing (r2's verified XOR scheme, 0 conflicts measured):
//   LDS row r at r*32 elems; 16B chunk q stored at qpos = q ^ ((r>>1)&3).
//   Staging: thread t -> row t>>2 (1024 thr x 16B = 16KB = full 256-row
//   tile), phys chunk t&3, content chunk (t&3)^((t>>3)&3)  [(row>>1)&3 ==
//   (t>>3)&3 for row = t>>2].  Frag read: qp = ((lane>>4)^((lane>>1)&3))*8.
// ---------------------------------------------------------------------------
__global__ __launch_bounds__(1024) void gemm_rowmax(const ushort* __restrict__ A,
                                                    const ushort* __restrict__ B,
                                                    unsigned* __restrict__ rowkey) {
    __shared__ __align__(16) ushort As[2][256 * 32];   // 2 x 16 KB
    __shared__ __align__(16) ushort Bs[2][256 * 32];   // 2 x 16 KB -> 64 KB total

    const int t    = threadIdx.x;
    const int lane = t & 63;
    const int w    = t >> 6;          // 0..15
    const int wm   = w >> 2;          // 0..3  (64-row quarter)
    const int wn   = w & 3;           // 0..3  (64-col quarter)

    // XCD-aware mapping (4096 blocks, %8==0): each XCD owns an 8-tile n-slice
    // (2048 cols of B = 3MB in its L2); n fastest for A-panel L2 reuse.
    const int bid   = blockIdx.x;
    const int xcd   = bid & 7;
    const int local = bid >> 3;                       // 0..511
    const int m0    = (local >> 3) * 256;             // 64 m-tiles
    const int n0    = (xcd * 8 + (local & 7)) * 256;  // 64 n-tiles

    f32x4 acc[4][4];
    #pragma unroll
    for (int i = 0; i < 4; ++i)
        #pragma unroll
        for (int j = 0; j < 4; ++j)
            acc[i][j] = (f32x4){0.f, 0.f, 0.f, 0.f};

    // staging: thread t -> row t>>2, phys 16B chunk t&3 at LDS byte t*16;
    // content k-chunk XOR-swizzled by row bits 1-2 (r2-verified, 0 conflicts)
    const int kq = ((t & 3) ^ ((t >> 3) & 3)) * 8;
    const ushort* ag = A + (size_t)(m0 + (t >> 2)) * C_DIM + kq;
    const ushort* bg = B + (size_t)(n0 + (t >> 2)) * C_DIM + kq;
    const int ldst = t * 8;                 // element offset into As/Bs

    // fragment reads: logical k-quad x = lane>>4 lives at quadpos
    // x ^ ((row>>1)&3); row = base + (lane&15), base % 16 == 0.
    const int qp    = ((lane >> 4) ^ ((lane >> 1) & 3)) * 8;
    const int a_off = (wm * 64 + (lane & 15)) * 32 + qp;
    const int b_off = (wn * 64 + (lane & 15)) * 32 + qp;

    // prologue: stage tile k=0 into buffer 0 (2 loads outstanding)
    async_ld16(ag, As[0] + ldst);
    async_ld16(bg, Bs[0] + ldst);

    int buf = 0;
    for (int k0 = 0; k0 < C_DIM - 32; k0 += 32) {
        // stage tile k+1 into buf^1 (its reads drained at prev iter's tail
        // barrier); issued BEFORE the wait so 2 loads ride across the barrier
        const int kn = k0 + 32, nb = buf ^ 1;
        async_ld16(ag + kn, As[nb] + ldst);
        async_ld16(bg + kn, Bs[nb] + ldst);

        asm volatile("s_waitcnt vmcnt(2)" ::: "memory");   // tile k landed
        __builtin_amdgcn_s_barrier();

        const ushort* Ab = As[buf];
        const ushort* Bb = Bs[buf];
        short8 af[4], bfr[4];
        #pragma unroll
        for (int mt = 0; mt < 4; ++mt)
            af[mt] = *(const short8*)(Ab + a_off + mt * 16 * 32);
        #pragma unroll
        for (int nt = 0; nt < 4; ++nt)
            bfr[nt] = *(const short8*)(Bb + b_off + nt * 16 * 32);

        __builtin_amdgcn_s_setprio(1);
        #pragma unroll
        for (int mt = 0; mt < 4; ++mt)
            #pragma unroll
            for (int nt = 0; nt < 4; ++nt)
                acc[mt][nt] = __builtin_amdgcn_mfma_f32_16x16x32_bf16(
                    af[mt], bfr[nt], acc[mt][nt], 0, 0, 0);
        __builtin_amdgcn_s_setprio(0);

        // all reads of buf drained before any wave stages into it next iter
        asm volatile("s_waitcnt lgkmcnt(0)" ::: "memory");
        __builtin_amdgcn_s_barrier();
        buf ^= 1;
    }

    // peeled final K-step: nothing left to stage; tile 23 (2 loads) is the
    // only outstanding -> vmcnt(0) is exact, and endpgm is clean.
    {
        asm volatile("s_waitcnt vmcnt(0)" ::: "memory");
        __builtin_amdgcn_s_barrier();
        const ushort* Ab = As[buf];
        const ushort* Bb = Bs[buf];
        short8 af[4], bfr[4];
        #pragma unroll
        for (int mt = 0; mt < 4; ++mt)
            af[mt] = *(const short8*)(Ab + a_off + mt * 16 * 32);
        #pragma unroll
        for (int nt = 0; nt < 4; ++nt)
            bfr[nt] = *(const short8*)(Bb + b_off + nt * 16 * 32);
        __builtin_amdgcn_s_setprio(1);
        #pragma unroll
        for (int mt = 0; mt < 4; ++mt)
            #pragma unroll
            for (int nt = 0; nt < 4; ++nt)
                acc[mt][nt] = __builtin_amdgcn_mfma_f32_16x16x32_bf16(
                    af[mt], bfr[nt], acc[mt][nt], 0, 0, 0);
        __builtin_amdgcn_s_setprio(0);
    }

    // epilogue: per-row max over this wave's 64 columns; waves sharing the
    // same m-rows (wn 0..3) merge via device-scope atomicMax.
    // C/D layout: col = lane&15, row = (lane>>4)*4 + reg.  (r0-verified)
    #pragma unroll
    for (int mt = 0; mt < 4; ++mt) {
        #pragma unroll
        for (int reg = 0; reg < 4; ++reg) {
            float v = fmaxf(fmaxf(acc[mt][0][reg], acc[mt][1][reg]),
                            fmaxf(acc[mt][2][reg], acc[mt][3][reg]));
            #pragma unroll
            for (int off = 1; off < 16; off <<= 1)
                v = fmaxf(v, __shfl_xor(v, off, 64));
            if ((lane & 15) == 0) {
                int m = m0 + wm * 64 + mt * 16 + (lane >> 4) * 4 + reg;
                unsigned u = __float_as_uint(v);
                u = (u & 0x80000000u) ? ~u : (u | 0x80000000u);  // order-preserving
                atomicMax(&rowkey[m], u);
            }
        }
    }
}

// ---------------------------------------------------------------------------
// Final: loss = 1 - mean(rowmax)
// ---------------------------------------------------------------------------
__global__ __launch_bounds__(1024) void finalize(const unsigned* __restrict__ rowkey,
                                                 float* __restrict__ out) {
    const int t = threadIdx.x;
    float s = 0.f;
    for (int i = t; i < N_DIM; i += 1024) {
        unsigned u = rowkey[i];
        float f = (u & 0x80000000u) ? __uint_as_float(u ^ 0x80000000u)
                                    : __uint_as_float(~u);
        s += f;
    }
    #pragma unroll
    for (int off = 32; off >= 1; off >>= 1)
        s += __shfl_down(s, off, 64);
    __shared__ float part[16];
    if ((t & 63) == 0) part[t >> 6] = s;
    __syncthreads();
    if (t == 0) {
        float tot = 0.f;
        #pragma unroll
        for (int i = 0; i < 16; ++i) tot += part[i];
        out[0] = 1.0f - tot * (1.0f / (float)N_DIM);
    }
}

extern "C" void kernel_launch(void* const* d_in, const int* in_sizes, int n_in,
                              void* d_out, int out_size, void* d_ws, size_t ws_size,
                              hipStream_t stream) {
    const float* F_r = (const float*)d_in[0];
    const float* F_s = (const float*)d_in[1];

    ushort*   Rt     = (ushort*)d_ws;                       // 16384 x 768 bf16
    ushort*   St     = Rt + (size_t)N_DIM * C_DIM;          // 16384 x 768 bf16
    unsigned* rowkey = (unsigned*)(St + (size_t)N_DIM * C_DIM);  // 16384 u32
    float*    out    = (float*)d_out;

    hipLaunchKernelGGL(norm_tr, dim3(N_DIM / 64, 2), dim3(256), 0, stream,
                       F_r, Rt, F_s, St);
    hipMemsetAsync(rowkey, 0, N_DIM * sizeof(unsigned), stream);
    hipLaunchKernelGGL(gemm_rowmax, dim3((N_DIM / 256) * (N_DIM / 256)), dim3(1024),
                       0, stream, Rt, St, rowkey);
    hipLaunchKernelGGL(finalize, dim3(1), dim3(1024), 0, stream, rowkey, out);
}